// Round 5
// baseline (37.522 us; speedup 1.0000x reference)
//
#include <hip/hip_runtime.h>
#include <hip/hip_bf16.h>
#include <math.h>

// B=2, L=5, C=32, H=48, W=176, NUM_ITER=1.
// Cuts: only i=0 slice matters (R1); conv = warped-half (per j) + ego-half (per b) (R1);
// conv+mlp on MFMA bf16 (R3); single fused kernel, per-block tile+halo warp in LDS,
// wave-specialized producer/consumer, double-buffered over j (R5). No workspace.
#define BB 2
#define LL 5
#define CC 32
#define HH 48
#define WW 176
#define HWs (HH * WW)     // 8448

#define TR 8              // inner tile rows
#define TC 8              // inner tile cols
#define HR 10             // halo rows
#define HC 10             // halo cols
#define PXS 40            // padded channel stride per halo pixel (bf16 units; 16B-aligned rows)
#define IMG_ELE (HR * HC * PXS)   // 4000 ushort per staged image

typedef __attribute__((ext_vector_type(8))) short bf16x8;
typedef __attribute__((ext_vector_type(4))) float f32x4;

__device__ __forceinline__ unsigned short f2bf(float v) {
    __hip_bfloat16 h = __float2bfloat16(v);   // RNE
    return *reinterpret_cast<unsigned short*>(&h);
}
__device__ __forceinline__ float bf2f(unsigned short u) {
    __hip_bfloat16 h = *reinterpret_cast<__hip_bfloat16*>(&u);
    return __bfloat162float(h);
}

// ---- bilinear weights/indices for grid_sample(align_corners=False, zeros pad) ----
__device__ __forceinline__ void bilin_weights(const float* __restrict__ Mp, int h, int w,
                                              int& o00, int& o10, int& o01, int& o11,
                                              float& a00, float& a10, float& a01, float& a11)
{
    float xs = (2.0f * (float)w + 1.0f) / (float)WW - 1.0f;
    float ys = (2.0f * (float)h + 1.0f) / (float)HH - 1.0f;
    float gx = Mp[0] * xs + Mp[1] * ys + Mp[2];
    float gy = Mp[3] * xs + Mp[4] * ys + Mp[5];
    float ix = ((gx + 1.0f) * (float)WW - 1.0f) * 0.5f;
    float iy = ((gy + 1.0f) * (float)HH - 1.0f) * 0.5f;
    float x0f = floorf(ix), y0f = floorf(iy);
    float wx = ix - x0f, wy = iy - y0f;
    float x1f = x0f + 1.0f, y1f = y0f + 1.0f;
    bool vx0 = (x0f >= 0.0f) && (x0f <= (float)(WW - 1));
    bool vx1 = (x1f >= 0.0f) && (x1f <= (float)(WW - 1));
    bool vy0 = (y0f >= 0.0f) && (y0f <= (float)(HH - 1));
    bool vy1 = (y1f >= 0.0f) && (y1f <= (float)(HH - 1));
    int xi0 = (int)fminf(fmaxf(x0f, 0.0f), (float)(WW - 1));
    int xi1 = (int)fminf(fmaxf(x1f, 0.0f), (float)(WW - 1));
    int yi0 = (int)fminf(fmaxf(y0f, 0.0f), (float)(HH - 1));
    int yi1 = (int)fminf(fmaxf(y1f, 0.0f), (float)(HH - 1));
    o00 = yi0 * WW + xi0;
    o10 = yi0 * WW + xi1;
    o01 = yi1 * WW + xi0;
    o11 = yi1 * WW + xi1;
    a00 = (vx0 && vy0) ? (1.0f - wx) * (1.0f - wy) : 0.0f;
    a10 = (vx1 && vy0) ? wx * (1.0f - wy) : 0.0f;
    a01 = (vx0 && vy1) ? (1.0f - wx) * wy : 0.0f;
    a11 = (vx1 && vy1) ? wx * wy : 0.0f;
}

// stage one (pixel, 8-channel-group) unit of an image tile into LDS.
// j < 0: ego copy of x[b][0]; j >= 0: bilinear warp of x[b][j] with M[b][0][j].
// OOB halo pixels (outside image) are zeroed == conv zero-padding.
__device__ __forceinline__ void stage_unit(const float* __restrict__ x,
                                           const float* __restrict__ Mp,
                                           int b, int j, int u, int r0, int c0,
                                           unsigned short* __restrict__ dst,
                                           float* __restrict__ maskrow)
{
    int px = u >> 2, cg = u & 3;
    int hr = px / HC, hc = px % HC;
    int gr = r0 + hr - 1, gc = c0 + hc - 1;
    unsigned short* dp = dst + px * PXS + cg * 8;
    if (gr < 0 || gr >= HH || gc < 0 || gc >= WW) {
        const bf16x8 z = {0, 0, 0, 0, 0, 0, 0, 0};
        *(bf16x8*)dp = z;
        return;
    }
    bf16x8 v8;
    if (j < 0) {
        const float* ip = x + ((size_t)(b * LL) * CC + cg * 8) * HWs + gr * WW + gc;
#pragma unroll
        for (int c = 0; c < 8; ++c)
            v8[c] = (short)f2bf(ip[(size_t)c * HWs]);
    } else {
        int o00, o10, o01, o11;
        float a00, a10, a01, a11;
        bilin_weights(Mp, gr, gc, o00, o10, o01, o11, a00, a10, a01, a11);
        if (cg == 0 && hr >= 1 && hr <= TR && hc >= 1 && hc <= TC)
            maskrow[(hr - 1) * TC + (hc - 1)] = a00 + a10 + a01 + a11;
        const float* ip = x + ((size_t)(b * LL + j) * CC + cg * 8) * HWs;
#pragma unroll
        for (int c = 0; c < 8; ++c) {
            const float* q = ip + (size_t)c * HWs;
            v8[c] = (short)f2bf(a00 * q[o00] + a10 * q[o10] + a01 * q[o01] + a11 * q[o11]);
        }
    }
    *(bf16x8*)dp = v8;
}

__global__ __launch_bounds__(512) void k_all(const float* __restrict__ x,
                                             const float* __restrict__ M,
                                             const float* __restrict__ msg_w,
                                             const float* __restrict__ msg_b,
                                             const float* __restrict__ mlp_w,
                                             const float* __restrict__ mlp_b,
                                             float* __restrict__ out)
{
    __shared__ unsigned short wmsg[2 * 9 * 32 * PXS];   // [half][tap][oc][ic @40] 46080 B
    __shared__ unsigned short wmlp[32 * PXS];           // [d][c @40]               2560 B
    __shared__ unsigned short ego[IMG_ELE];             // [halo px][ch @40]        8000 B
    __shared__ unsigned short jbuf[2 * IMG_ELE];        // double buffer           16000 B
    __shared__ float maskl[LL][TR * TC];                //                          1280 B

    const int tid = threadIdx.x;
    const int b  = blockIdx.z;
    const int r0 = blockIdx.y * TR;
    const int c0 = blockIdx.x * TC;
    const float* Mb = M + (size_t)b * LL * LL * 6;      // M[b][0][j] = Mb + j*6

    // ---- phase 0: pack weights to LDS bf16 (all threads) ----
    for (int i = tid; i < 2 * 9 * 32 * 32; i += 512) {
        int half = i / (9 * 32 * 32), r = i % (9 * 32 * 32);
        int tap = r / 1024, r2 = r & 1023, oc = r2 >> 5, ic = r2 & 31;
        wmsg[((half * 9 + tap) * 32 + oc) * PXS + ic] =
            f2bf(msg_w[(size_t)oc * 576 + (size_t)(half * 32 + ic) * 9 + tap]);
    }
    for (int i = tid; i < 32 * 32; i += 512)
        wmlp[(i >> 5) * PXS + (i & 31)] = f2bf(mlp_w[i]);

    // ---- phase 0b: stage ego tile + j=0 warped tile (all threads) ----
    for (int u = tid; u < 800; u += 512) {
        if (u < 400) stage_unit(x, nullptr, b, -1, u, r0, c0, ego, nullptr);
        else         stage_unit(x, Mb, b, 0, u - 400, r0, c0, jbuf, maskl[0]);
    }
    __syncthreads();

    const int wv   = tid >> 6;     // 0..7
    const int lane = tid & 63;
    const int lo   = lane & 15;
    const int kblk = lane >> 4;
    const bool isconv = (wv < 4);

    f32x4 acce[2] = {};
    f32x4 agg[2];
#pragma unroll
    for (int r = 0; r < 4; ++r) { agg[0][r] = -INFINITY; agg[1][r] = -INFINITY; }

    for (int j = 0; j < LL; ++j) {
        if (!isconv) {
            if (j < 4) {   // stage j+1 into the other buffer (conv j reads buf[j&1])
                unsigned short* dstb = jbuf + ((j + 1) & 1) * IMG_ELE;
                const float* Mp = Mb + (size_t)(j + 1) * 6;
                for (int u = tid - 256; u < 400; u += 256)
                    stage_unit(x, Mp, b, j + 1, u, r0, c0, dstb, maskl[j + 1]);
            }
        } else {
            if (j == 0) {
                // ego half-conv (+ conv bias)
#pragma unroll
                for (int tap = 0; tap < 9; ++tap) {
                    int dy = tap / 3 - 1, dx = tap % 3 - 1;
                    int hp = (1 + 2 * wv + (lo >> 3) + dy) * HC + (1 + (lo & 7) + dx);
                    bf16x8 Af = *(const bf16x8*)(ego + hp * PXS + kblk * 8);
#pragma unroll
                    for (int nt = 0; nt < 2; ++nt) {
                        bf16x8 Bf = *(const bf16x8*)(wmsg + (size_t)((9 + tap) * 32 + nt * 16 + lo) * PXS + kblk * 8);
                        acce[nt] = __builtin_amdgcn_mfma_f32_16x16x32_bf16(Af, Bf, acce[nt], 0, 0, 0);
                    }
                }
                float b0 = msg_b[lo], b1 = msg_b[16 + lo];
#pragma unroll
                for (int r = 0; r < 4; ++r) { acce[0][r] += b0; acce[1][r] += b1; }
            }
            // warped half-conv for j
            const unsigned short* jb = jbuf + (j & 1) * IMG_ELE;
            f32x4 acc[2] = {};
#pragma unroll
            for (int tap = 0; tap < 9; ++tap) {
                int dy = tap / 3 - 1, dx = tap % 3 - 1;
                int hp = (1 + 2 * wv + (lo >> 3) + dy) * HC + (1 + (lo & 7) + dx);
                bf16x8 Af = *(const bf16x8*)(jb + hp * PXS + kblk * 8);
#pragma unroll
                for (int nt = 0; nt < 2; ++nt) {
                    bf16x8 Bf = *(const bf16x8*)(wmsg + (size_t)(tap * 32 + nt * 16 + lo) * PXS + kblk * 8);
                    acc[nt] = __builtin_amdgcn_mfma_f32_16x16x32_bf16(Af, Bf, acc[nt], 0, 0, 0);
                }
            }
            f32x4 mk = *(const f32x4*)&maskl[j][wv * 16 + kblk * 4];
#pragma unroll
            for (int nt = 0; nt < 2; ++nt)
#pragma unroll
                for (int r = 0; r < 4; ++r)
                    agg[nt][r] = fmaxf(agg[nt][r], (acc[nt][r] + acce[nt][r]) * mk[r]);
        }
        if (j < 4) __syncthreads();
    }
    __syncthreads();   // all conv reads of jbuf done -> fl may overlay jbuf

    if (isconv) {
        // f = agg + x0(ego, bf16) -> per-wave LDS transpose region (overlaid on jbuf)
        float* fl = ((float*)jbuf) + wv * (16 * PXS);
#pragma unroll
        for (int nt = 0; nt < 2; ++nt)
#pragma unroll
            for (int r = 0; r < 4; ++r) {
                int m = kblk * 4 + r;
                int hp = (1 + 2 * wv + (m >> 3)) * HC + 1 + (m & 7);
                float skip = bf2f(ego[hp * PXS + nt * 16 + lo]);
                fl[m * PXS + nt * 16 + lo] = agg[nt][r] + skip;
            }
        // read back own wave's region (same-wave: lgkmcnt ordering, no barrier needed)
        f32x4 q0 = *(const f32x4*)&fl[lo * PXS + kblk * 8];
        f32x4 q1 = *(const f32x4*)&fl[lo * PXS + kblk * 8 + 4];
        bf16x8 Afm;
#pragma unroll
        for (int e = 0; e < 4; ++e) {
            Afm[e]     = (short)f2bf(q0[e]);
            Afm[4 + e] = (short)f2bf(q1[e]);
        }
#pragma unroll
        for (int nt2 = 0; nt2 < 2; ++nt2) {
            bf16x8 Bm = *(const bf16x8*)(wmlp + (size_t)(nt2 * 16 + lo) * PXS + kblk * 8);
            f32x4 om = {};
            om = __builtin_amdgcn_mfma_f32_16x16x32_bf16(Afm, Bm, om, 0, 0, 0);
            float mb2 = mlp_b[nt2 * 16 + lo];
            int d = nt2 * 16 + lo;
#pragma unroll
            for (int r = 0; r < 4; ++r) {
                int m = kblk * 4 + r;
                int gr = r0 + 2 * wv + (m >> 3);
                int gc = c0 + (m & 7);
                out[((size_t)(b * CC + d)) * HWs + gr * WW + gc] = om[r] + mb2;
            }
        }
    }
}

extern "C" void kernel_launch(void* const* d_in, const int* in_sizes, int n_in,
                              void* d_out, int out_size, void* d_ws, size_t ws_size,
                              hipStream_t stream)
{
    (void)in_sizes; (void)n_in; (void)out_size; (void)d_ws; (void)ws_size;
    const float* x     = (const float*)d_in[0];
    // d_in[1] = record_len (unused by reference)
    const float* M     = (const float*)d_in[2];
    const float* msg_w = (const float*)d_in[3];
    const float* msg_b = (const float*)d_in[4];
    const float* mlp_w = (const float*)d_in[5];
    const float* mlp_b = (const float*)d_in[6];
    float* out = (float*)d_out;

    dim3 g(WW / TC, HH / TR, BB);   // (22, 6, 2) = 264 blocks
    k_all<<<g, 512, 0, stream>>>(x, M, msg_w, msg_b, mlp_w, mlp_b, out);
}

// Round 6
// 34.961 us; speedup vs baseline: 1.0733x; 1.0733x over previous
//
#include <hip/hip_runtime.h>
#include <hip/hip_bf16.h>
#include <math.h>

// B=2, L=5, C=32, H=48, W=176, NUM_ITER=1.
// Cuts: only i=0 slice matters (R1); conv = warped-half (per j) + ego-half (per b) (R1);
// conv+mlp on MFMA bf16 (R3); single fused kernel (R5).
// R6: no wave specialization (all 4 waves stage AND conv), T14 async-stage split
// (issue gather loads -> conv -> cvt+ds_write), coalesced b64 weight pack,
// masks precomputed in phase 0. LDS 73.9 KB -> 2 blocks/CU.
#define BB 2
#define LL 5
#define CC 32
#define HH 48
#define WW 176
#define HWs (HH * WW)     // 8448

#define TR 8              // inner tile rows
#define TC 8              // inner tile cols
#define HR 10             // halo rows
#define HC 10             // halo cols
#define PXS 40            // padded channel stride per halo pixel (bf16 units; 80B rows, 16B-aligned)
#define IMG_ELE (HR * HC * PXS)   // 4000 ushort per staged image

typedef __attribute__((ext_vector_type(8))) short bf16x8;
typedef __attribute__((ext_vector_type(4))) short bf16x4;
typedef __attribute__((ext_vector_type(4))) float f32x4;

__device__ __forceinline__ unsigned short f2bf(float v) {
    __hip_bfloat16 h = __float2bfloat16(v);   // RNE
    return *reinterpret_cast<unsigned short*>(&h);
}
__device__ __forceinline__ float bf2f(unsigned short u) {
    __hip_bfloat16 h = *reinterpret_cast<__hip_bfloat16*>(&u);
    return __bfloat162float(h);
}

// ---- bilinear weights/indices for grid_sample(align_corners=False, zeros pad) ----
__device__ __forceinline__ void bilin_weights(const float* __restrict__ Mp, int h, int w,
                                              int& o00, int& o10, int& o01, int& o11,
                                              float& a00, float& a10, float& a01, float& a11)
{
    float xs = (2.0f * (float)w + 1.0f) / (float)WW - 1.0f;
    float ys = (2.0f * (float)h + 1.0f) / (float)HH - 1.0f;
    float gx = Mp[0] * xs + Mp[1] * ys + Mp[2];
    float gy = Mp[3] * xs + Mp[4] * ys + Mp[5];
    float ix = ((gx + 1.0f) * (float)WW - 1.0f) * 0.5f;
    float iy = ((gy + 1.0f) * (float)HH - 1.0f) * 0.5f;
    float x0f = floorf(ix), y0f = floorf(iy);
    float wx = ix - x0f, wy = iy - y0f;
    float x1f = x0f + 1.0f, y1f = y0f + 1.0f;
    bool vx0 = (x0f >= 0.0f) && (x0f <= (float)(WW - 1));
    bool vx1 = (x1f >= 0.0f) && (x1f <= (float)(WW - 1));
    bool vy0 = (y0f >= 0.0f) && (y0f <= (float)(HH - 1));
    bool vy1 = (y1f >= 0.0f) && (y1f <= (float)(HH - 1));
    int xi0 = (int)fminf(fmaxf(x0f, 0.0f), (float)(WW - 1));
    int xi1 = (int)fminf(fmaxf(x1f, 0.0f), (float)(WW - 1));
    int yi0 = (int)fminf(fmaxf(y0f, 0.0f), (float)(HH - 1));
    int yi1 = (int)fminf(fmaxf(y1f, 0.0f), (float)(HH - 1));
    o00 = yi0 * WW + xi0;
    o10 = yi0 * WW + xi1;
    o01 = yi1 * WW + xi0;
    o11 = yi1 * WW + xi1;
    a00 = (vx0 && vy0) ? (1.0f - wx) * (1.0f - wy) : 0.0f;
    a10 = (vx1 && vy0) ? wx * (1.0f - wy) : 0.0f;
    a01 = (vx0 && vy1) ? (1.0f - wx) * wy : 0.0f;
    a11 = (vx1 && vy1) ? wx * wy : 0.0f;
}

// immediate stage (phase 0): one (halo-pixel, 8-ch-group) unit; j<0 = ego copy.
__device__ __forceinline__ void stage_now(const float* __restrict__ x,
                                          const float* __restrict__ Mp,
                                          int b, int j, int u, int r0, int c0,
                                          unsigned short* __restrict__ dst)
{
    int px = u >> 2, cg = u & 3;
    int hr = px / HC, hc = px % HC;
    int gr = r0 + hr - 1, gc = c0 + hc - 1;
    unsigned short* dp = dst + px * PXS + cg * 8;
    if (gr < 0 || gr >= HH || gc < 0 || gc >= WW) {
        const bf16x8 z = {0, 0, 0, 0, 0, 0, 0, 0};
        *(bf16x8*)dp = z;
        return;
    }
    bf16x8 v8;
    if (j < 0) {
        const float* ip = x + ((size_t)(b * LL) * CC + cg * 8) * HWs + gr * WW + gc;
#pragma unroll
        for (int c = 0; c < 8; ++c)
            v8[c] = (short)f2bf(ip[(size_t)c * HWs]);
    } else {
        int o00, o10, o01, o11;
        float a00, a10, a01, a11;
        bilin_weights(Mp, gr, gc, o00, o10, o01, o11, a00, a10, a01, a11);
        const float* ip = x + ((size_t)(b * LL + j) * CC + cg * 8) * HWs;
#pragma unroll
        for (int c = 0; c < 8; ++c) {
            const float* q = ip + (size_t)c * HWs;
            v8[c] = (short)f2bf(a00 * q[o00] + a10 * q[o10] + a01 * q[o01] + a11 * q[o11]);
        }
    }
    *(bf16x8*)dp = v8;
}

// T14 part A: compute addresses, issue 32 gather loads into regs (no cvt yet)
__device__ __forceinline__ void pref_A(const float* __restrict__ x,
                                       const float* __restrict__ Mp,
                                       int b, int j, int px, int cg, int r0, int c0,
                                       float* __restrict__ t, float* __restrict__ a, bool& v)
{
    int hr = px / HC, hc = px % HC;
    int gr = r0 + hr - 1, gc = c0 + hc - 1;
    v = !(gr < 0 || gr >= HH || gc < 0 || gc >= WW);
    if (!v) return;
    int o00, o10, o01, o11;
    bilin_weights(Mp, gr, gc, o00, o10, o01, o11, a[0], a[1], a[2], a[3]);
    const float* ip = x + ((size_t)(b * LL + j) * CC + cg * 8) * HWs;
#pragma unroll
    for (int c = 0; c < 8; ++c) {
        const float* q = ip + (size_t)c * HWs;
        t[c * 4 + 0] = q[o00];
        t[c * 4 + 1] = q[o10];
        t[c * 4 + 2] = q[o01];
        t[c * 4 + 3] = q[o11];
    }
}

// T14 part C: combine taps, convert, ds_write
__device__ __forceinline__ void pref_C(unsigned short* __restrict__ dst,
                                       int px, int cg,
                                       const float* __restrict__ t,
                                       const float* __restrict__ a, bool v)
{
    bf16x8 v8 = {0, 0, 0, 0, 0, 0, 0, 0};
    if (v) {
#pragma unroll
        for (int c = 0; c < 8; ++c)
            v8[c] = (short)f2bf(a[0] * t[c * 4] + a[1] * t[c * 4 + 1] +
                                a[2] * t[c * 4 + 2] + a[3] * t[c * 4 + 3]);
    }
    *(bf16x8*)(dst + px * PXS + cg * 8) = v8;
}

__global__ __launch_bounds__(256) void k_all(const float* __restrict__ x,
                                             const float* __restrict__ M,
                                             const float* __restrict__ msg_w,
                                             const float* __restrict__ msg_b,
                                             const float* __restrict__ mlp_w,
                                             const float* __restrict__ mlp_b,
                                             float* __restrict__ out)
{
    __shared__ unsigned short wmsg[2 * 9 * 32 * PXS];   // [half][tap][oc][ic @40] 46080 B
    __shared__ unsigned short wmlp[32 * PXS];           //                          2560 B
    __shared__ unsigned short ego[IMG_ELE];             //                          8000 B
    __shared__ alignas(16) unsigned short jbuf[2][IMG_ELE];   // double buffer    16000 B
    __shared__ float maskl[LL][64];                     //                          1280 B

    const int tid = threadIdx.x;
    const int b  = blockIdx.z;
    const int r0 = blockIdx.y * TR;
    const int c0 = blockIdx.x * TC;
    const float* Mb = M + (size_t)b * LL * LL * 6;      // M[b][0][j] = Mb + j*6

    // ---- phase 0a: msg_w -> LDS bf16, b64 writes, ordered loads ----
    // quad q: ic4=(q&7)*4, oc=(q>>3)&31, half*9+tap = q>>8
#pragma unroll
    for (int k = 0; k < 18; ++k) {
        int q = k * 256 + tid;
        int ic4 = (q & 7) * 4;
        int oc  = (q >> 3) & 31;
        int ht  = q >> 8;
        int tap = ht % 9, half = ht / 9;
        bf16x4 w4;
#pragma unroll
        for (int e = 0; e < 4; ++e)
            w4[e] = (short)f2bf(msg_w[(size_t)oc * 576 + (size_t)(half * 32 + ic4 + e) * 9 + tap]);
        *(bf16x4*)(wmsg + (size_t)(ht * 32 + oc) * PXS + ic4) = w4;
    }
    // ---- phase 0b: mlp_w -> LDS bf16 ----
    {
        int q = tid;                 // 256 quads cover 1024 elems
        int c4 = (q & 7) * 4, d = q >> 3;
        bf16x4 w4;
#pragma unroll
        for (int e = 0; e < 4; ++e)
            w4[e] = (short)f2bf(mlp_w[(size_t)d * 32 + c4 + e]);
        *(bf16x4*)(wmlp + (size_t)d * PXS + c4) = w4;
    }
    // ---- phase 0c: masks for all j (inner 64 px, conv's m-index order) ----
    for (int i = tid; i < LL * 64; i += 256) {
        int j = i >> 6, q = i & 63;
        int gr = r0 + 2 * (q >> 4) + ((q & 15) >> 3);
        int gc = c0 + (q & 7);
        int o00, o10, o01, o11;
        float a00, a10, a01, a11;
        bilin_weights(Mb + (size_t)j * 6, gr, gc, o00, o10, o01, o11, a00, a10, a01, a11);
        maskl[j][q] = a00 + a10 + a01 + a11;
    }
    // ---- phase 0d: stage ego + j=0 ----
    for (int u = tid; u < 800; u += 256) {
        if (u < 400) stage_now(x, nullptr, b, -1, u, r0, c0, ego);
        else         stage_now(x, Mb, b, 0, u - 400, r0, c0, jbuf[0]);
    }
    __syncthreads();

    const int wv   = tid >> 6;     // 0..3
    const int lane = tid & 63;
    const int lo   = lane & 15;
    const int kblk = lane >> 4;

    const int px1 = tid >> 2,        cg1 = tid & 3;   // unit 1: px 0..63
    const int px2 = 64 + (tid >> 2), cg2 = tid & 3;   // unit 2: px 64..99 (tid<144)
    const bool has2 = (tid < 144);

    f32x4 acce[2] = {};
    f32x4 agg[2];
#pragma unroll
    for (int r = 0; r < 4; ++r) { agg[0][r] = -INFINITY; agg[1][r] = -INFINITY; }

    float t1[32], a1[4]; bool v1 = false;
    float t2[32], a2[4]; bool v2 = false;

    for (int j = 0; j < LL; ++j) {
        // A) issue gather loads for j+1 into regs (latency hides under conv below)
        if (j < 4) {
            pref_A(x, Mb + (size_t)(j + 1) * 6, b, j + 1, px1, cg1, r0, c0, t1, a1, v1);
            if (has2) pref_A(x, Mb + (size_t)(j + 1) * 6, b, j + 1, px2, cg2, r0, c0, t2, a2, v2);
        }

        // B) conv j
        if (j == 0) {
            // ego half-conv (+ conv bias)
#pragma unroll
            for (int tap = 0; tap < 9; ++tap) {
                int dy = tap / 3 - 1, dx = tap % 3 - 1;
                int hp = (1 + 2 * wv + (lo >> 3) + dy) * HC + (1 + (lo & 7) + dx);
                bf16x8 Af = *(const bf16x8*)(ego + hp * PXS + kblk * 8);
#pragma unroll
                for (int nt = 0; nt < 2; ++nt) {
                    bf16x8 Bf = *(const bf16x8*)(wmsg + (size_t)((9 + tap) * 32 + nt * 16 + lo) * PXS + kblk * 8);
                    acce[nt] = __builtin_amdgcn_mfma_f32_16x16x32_bf16(Af, Bf, acce[nt], 0, 0, 0);
                }
            }
            float b0 = msg_b[lo], b1 = msg_b[16 + lo];
#pragma unroll
            for (int r = 0; r < 4; ++r) { acce[0][r] += b0; acce[1][r] += b1; }
        }
        {
            const unsigned short* jb = jbuf[j & 1];
            f32x4 acc[2] = {};
#pragma unroll
            for (int tap = 0; tap < 9; ++tap) {
                int dy = tap / 3 - 1, dx = tap % 3 - 1;
                int hp = (1 + 2 * wv + (lo >> 3) + dy) * HC + (1 + (lo & 7) + dx);
                bf16x8 Af = *(const bf16x8*)(jb + hp * PXS + kblk * 8);
#pragma unroll
                for (int nt = 0; nt < 2; ++nt) {
                    bf16x8 Bf = *(const bf16x8*)(wmsg + (size_t)(tap * 32 + nt * 16 + lo) * PXS + kblk * 8);
                    acc[nt] = __builtin_amdgcn_mfma_f32_16x16x32_bf16(Af, Bf, acc[nt], 0, 0, 0);
                }
            }
            f32x4 mk = *(const f32x4*)&maskl[j][wv * 16 + kblk * 4];
#pragma unroll
            for (int nt = 0; nt < 2; ++nt)
#pragma unroll
                for (int r = 0; r < 4; ++r)
                    agg[nt][r] = fmaxf(agg[nt][r], (acc[nt][r] + acce[nt][r]) * mk[r]);
        }

        // C) convert + LDS-write j+1
        if (j < 4) {
            pref_C(jbuf[(j + 1) & 1], px1, cg1, t1, a1, v1);
            if (has2) pref_C(jbuf[(j + 1) & 1], px2, cg2, t2, a2, v2);
        }
        __syncthreads();
    }

    // ---- epilogue: f = agg + x0(ego) -> per-wave LDS transpose (overlay jbuf) -> mlp MFMA ----
    float* fl = ((float*)jbuf) + wv * (16 * PXS);
#pragma unroll
    for (int nt = 0; nt < 2; ++nt)
#pragma unroll
        for (int r = 0; r < 4; ++r) {
            int m = kblk * 4 + r;
            int hp = (1 + 2 * wv + (m >> 3)) * HC + 1 + (m & 7);
            float skip = bf2f(ego[hp * PXS + nt * 16 + lo]);
            fl[m * PXS + nt * 16 + lo] = agg[nt][r] + skip;
        }
    // same-wave read-back (lgkmcnt ordering; no cross-wave sharing)
    f32x4 q0 = *(const f32x4*)&fl[lo * PXS + kblk * 8];
    f32x4 q1 = *(const f32x4*)&fl[lo * PXS + kblk * 8 + 4];
    bf16x8 Afm;
#pragma unroll
    for (int e = 0; e < 4; ++e) {
        Afm[e]     = (short)f2bf(q0[e]);
        Afm[4 + e] = (short)f2bf(q1[e]);
    }
#pragma unroll
    for (int nt2 = 0; nt2 < 2; ++nt2) {
        bf16x8 Bm = *(const bf16x8*)(wmlp + (size_t)(nt2 * 16 + lo) * PXS + kblk * 8);
        f32x4 om = {};
        om = __builtin_amdgcn_mfma_f32_16x16x32_bf16(Afm, Bm, om, 0, 0, 0);
        float mb2 = mlp_b[nt2 * 16 + lo];
        int d = nt2 * 16 + lo;
#pragma unroll
        for (int r = 0; r < 4; ++r) {
            int m = kblk * 4 + r;
            int gr = r0 + 2 * wv + (m >> 3);
            int gc = c0 + (m & 7);
            out[((size_t)(b * CC + d)) * HWs + gr * WW + gc] = om[r] + mb2;
        }
    }
}

extern "C" void kernel_launch(void* const* d_in, const int* in_sizes, int n_in,
                              void* d_out, int out_size, void* d_ws, size_t ws_size,
                              hipStream_t stream)
{
    (void)in_sizes; (void)n_in; (void)out_size; (void)d_ws; (void)ws_size;
    const float* x     = (const float*)d_in[0];
    // d_in[1] = record_len (unused by reference)
    const float* M     = (const float*)d_in[2];
    const float* msg_w = (const float*)d_in[3];
    const float* msg_b = (const float*)d_in[4];
    const float* mlp_w = (const float*)d_in[5];
    const float* mlp_b = (const float*)d_in[6];
    float* out = (float*)d_out;

    dim3 g(WW / TC, HH / TR, BB);   // (22, 6, 2) = 264 blocks
    k_all<<<g, 256, 0, stream>>>(x, M, msg_w, msg_b, mlp_w, mlp_b, out);
}